// Round 10
// baseline (300.820 us; speedup 1.0000x reference)
//
#include <hip/hip_runtime.h>

// VanillaGNN: out = A @ relu(A @ (x@W1)) @ W2, A[dst,src]=vals, all inputs f32.
// N=100000, E=1600000, IN=128, HID=128, OUT=64.
// CSR build via atomic-free two-level counting sort (LDS atomics + scans).
// bf16 MFMA GEMMs writing SLICE-MAJOR h ([slice][N][16 or 8] bf16), and
// feature-sliced XCD-pinned SpMM: block b -> slice b%8 (round-robin = XCD id),
// so each XCD gathers only from its own 3.2MB/1.6MB L2-resident slice.
// Attacks the 185MB FETCH floor = h replicated across 8 non-coherent L2s.

#define IN_CH  128
#define HID_CH 128
#define OUT_CH 64

typedef __attribute__((ext_vector_type(8))) short  bfrag8;   // 8 bf16 (MFMA A/B)
typedef __attribute__((ext_vector_type(4))) float  f32x4;    // MFMA C/D
typedef __attribute__((ext_vector_type(4))) unsigned short us4;
typedef __attribute__((ext_vector_type(8))) unsigned short us8;

__device__ __forceinline__ unsigned short f2bf(float f) {
    unsigned u = __float_as_uint(f);
    u += 0x7FFFu + ((u >> 16) & 1u);   // round-to-nearest-even
    return (unsigned short)(u >> 16);
}
__device__ __forceinline__ float bf2f(unsigned short u) {
    return __uint_as_float(((unsigned)u) << 16);
}

// ---------------- CSR build (no global atomics) ----------------

__global__ __launch_bounds__(256) void cnt1(const int* __restrict__ dst,
                                            int* __restrict__ bcnt,
                                            int E, int CH, int NBUCK, int G1) {
    __shared__ int hist[512];
    const int blk = blockIdx.x, t = threadIdx.x;
    for (int j = t; j < NBUCK; j += 256) hist[j] = 0;
    __syncthreads();
    const int lo = blk * CH;
    const int hi = (lo + CH < E) ? lo + CH : E;
    for (int i = lo + t; i < hi; i += 256)
        atomicAdd(&hist[dst[i] >> 8], 1);
    __syncthreads();
    for (int j = t; j < NBUCK; j += 256) bcnt[(size_t)j * G1 + blk] = hist[j];
}

__global__ __launch_bounds__(1024) void scanA(const int* __restrict__ counts,
                                              int* __restrict__ excl,
                                              int* __restrict__ btot, int n) {
    __shared__ int wex[16];
    int t = threadIdx.x, lane = t & 63, w = t >> 6;
    int i = blockIdx.x * 1024 + t;
    int v = (i < n) ? counts[i] : 0;
    int s = v;
    #pragma unroll
    for (int d = 1; d < 64; d <<= 1) {
        int u = __shfl_up(s, d, 64);
        if (lane >= d) s += u;
    }
    if (lane == 63) wex[w] = s;
    __syncthreads();
    if (t == 0) {
        int run = 0;
        #pragma unroll
        for (int j = 0; j < 16; ++j) { int x = wex[j]; wex[j] = run; run += x; }
        btot[blockIdx.x] = run;
    }
    __syncthreads();
    if (i < n) excl[i] = wex[w] + (s - v);
}

__global__ __launch_bounds__(128) void scanB(int* __restrict__ btot, int nblk) {
    __shared__ int t0;
    int t = threadIdx.x, lane = t & 63, w = t >> 6;
    int v = (t < nblk) ? btot[t] : 0;
    int s = v;
    #pragma unroll
    for (int d = 1; d < 64; d <<= 1) {
        int u = __shfl_up(s, d, 64);
        if (lane >= d) s += u;
    }
    if (w == 0 && lane == 63) t0 = s;
    __syncthreads();
    int excl = (s - v) + (w ? t0 : 0);
    if (t < nblk) btot[t] = excl;
}

__global__ __launch_bounds__(1024) void scanC2(int* __restrict__ off,
                                               const int* __restrict__ btot, int n) {
    int i = blockIdx.x * 1024 + threadIdx.x;
    if (i < n) off[i] += btot[blockIdx.x];
}

__global__ void bbk(const int* __restrict__ off, int* __restrict__ bb,
                    int NBUCK, int G1, int E) {
    int t = threadIdx.x;
    if (t < NBUCK) bb[t] = off[(size_t)t * G1];
    if (t == NBUCK) bb[t] = E;
}

__global__ __launch_bounds__(256) void scat1(const int* __restrict__ src,
                                             const int* __restrict__ dst,
                                             const float* __restrict__ ev,
                                             const int* __restrict__ off,
                                             int2* __restrict__ ebuf,
                                             int E, int CH, int NBUCK, int G1) {
    __shared__ int cur[512];
    const int blk = blockIdx.x, t = threadIdx.x;
    for (int j = t; j < NBUCK; j += 256) cur[j] = off[(size_t)j * G1 + blk];
    __syncthreads();
    const int lo = blk * CH;
    const int hi = (lo + CH < E) ? lo + CH : E;
    for (int i = lo + t; i < hi; i += 256) {
        int d = dst[i];
        int pos = atomicAdd(&cur[d >> 8], 1);
        ebuf[pos] = make_int2(((d & 255) << 24) | src[i], __float_as_int(ev[i]));
    }
}

__global__ __launch_bounds__(256) void sort2(const int2* __restrict__ ebuf,
                                             const int* __restrict__ bb,
                                             int2* __restrict__ sval,
                                             int* __restrict__ row_ptr,
                                             int N, int NBUCK, int E) {
    __shared__ int hist[256];
    __shared__ int cur[256];
    __shared__ int wsum[4];
    const int b = blockIdx.x, t = threadIdx.x;
    const int base = bb[b];
    const int cnt = bb[b + 1] - base;
    hist[t] = 0;
    __syncthreads();
    for (int i = base + t; i < base + cnt; i += 256)
        atomicAdd(&hist[(unsigned)ebuf[i].x >> 24], 1);
    __syncthreads();
    int lane = t & 63, w = t >> 6;
    int v = hist[t], s = v;
    #pragma unroll
    for (int d = 1; d < 64; d <<= 1) {
        int u = __shfl_up(s, d, 64);
        if (lane >= d) s += u;
    }
    if (lane == 63) wsum[w] = s;
    __syncthreads();
    if (t == 0) {
        int run = 0;
        #pragma unroll
        for (int j = 0; j < 4; ++j) { int x = wsum[j]; wsum[j] = run; run += x; }
    }
    __syncthreads();
    int excl = wsum[w] + (s - v);
    int node = (b << 8) + t;
    if (node < N) row_ptr[node] = base + excl;
    if (b == NBUCK - 1 && t == 0) row_ptr[N] = E;
    cur[t] = excl;
    __syncthreads();
    for (int i = base + t; i < base + cnt; i += 256) {
        int2 e = ebuf[i];
        int bin = (unsigned)e.x >> 24;
        int pos = base + atomicAdd(&cur[bin], 1);
        sval[pos] = make_int2(e.x & 0xFFFFFF, e.y);
    }
}

// ---------------- weight cast+transpose (tiny) ----------------

__global__ void castT_w1(const float* __restrict__ W, unsigned short* __restrict__ WT) {
    int idx = blockIdx.x * 256 + threadIdx.x;          // 16384 elems
    int n = idx >> 7, k = idx & 127;                   // WT[n][k] = W[k][n]
    WT[n * 128 + k] = f2bf(W[k * 128 + n]);
}
__global__ void castT_w2(const float* __restrict__ W, unsigned short* __restrict__ WT) {
    int idx = blockIdx.x * 256 + threadIdx.x;          // 8192 elems
    int n = idx >> 7, k = idx & 127;                   // WT[n][k] = W[k*64 + n]
    WT[n * 128 + k] = f2bf(W[(size_t)k * OUT_CH + n]);
}

// ---------------- GEMM1: h1s = bf16(x @ W1), slice-major out [8][M][16] ----------------

__global__ __launch_bounds__(256) void gemm1_mfma(const float* __restrict__ X,
                                                  const unsigned short* __restrict__ W1T,
                                                  unsigned short* __restrict__ H1S, int M) {
    __shared__ __align__(16) unsigned short As[128 * 136];
    __shared__ __align__(16) unsigned short Bs[128 * 136];
    const int tid = threadIdx.x;
    const int lane = tid & 63;
    const int w = tid >> 6;
    const int row0 = blockIdx.x * 128;

    #pragma unroll
    for (int l = 0; l < 16; ++l) {
        int f = tid + l * 256;
        int r = f >> 5, c4 = f & 31;
        int row = row0 + r;
        float4 v = make_float4(0.f, 0.f, 0.f, 0.f);
        if (row < M) v = *reinterpret_cast<const float4*>(&X[(size_t)row * IN_CH + c4 * 4]);
        us4 o; o[0] = f2bf(v.x); o[1] = f2bf(v.y); o[2] = f2bf(v.z); o[3] = f2bf(v.w);
        *reinterpret_cast<us4*>(&As[r * 136 + c4 * 4]) = o;
    }
    #pragma unroll
    for (int l = 0; l < 8; ++l) {
        int f = tid + l * 256;
        int n = f >> 4, k8 = f & 15;
        us8 v = *reinterpret_cast<const us8*>(&W1T[n * 128 + k8 * 8]);
        *reinterpret_cast<us8*>(&Bs[n * 136 + k8 * 8]) = v;
    }
    __syncthreads();

    f32x4 acc[2][8] = {};
    const int lr = lane & 15;
    const int kb = (lane >> 4) * 8;
    #pragma unroll
    for (int kk = 0; kk < 4; ++kk) {
        bfrag8 a0 = *reinterpret_cast<const bfrag8*>(&As[(w * 32 + lr) * 136 + kk * 32 + kb]);
        bfrag8 a1 = *reinterpret_cast<const bfrag8*>(&As[(w * 32 + 16 + lr) * 136 + kk * 32 + kb]);
        #pragma unroll
        for (int ni = 0; ni < 8; ++ni) {
            bfrag8 b = *reinterpret_cast<const bfrag8*>(&Bs[(ni * 16 + lr) * 136 + kk * 32 + kb]);
            acc[0][ni] = __builtin_amdgcn_mfma_f32_16x16x32_bf16(a0, b, acc[0][ni], 0, 0, 0);
            acc[1][ni] = __builtin_amdgcn_mfma_f32_16x16x32_bf16(a1, b, acc[1][ni], 0, 0, 0);
        }
    }
    // epilogue: feature ni*16+lr of row -> slice ni: H1S[(ni*M + row)*16 + lr]
    const int rb = row0 + w * 32 + (lane >> 4) * 4;
    #pragma unroll
    for (int mi = 0; mi < 2; ++mi)
        #pragma unroll
        for (int j = 0; j < 4; ++j) {
            int row = rb + mi * 16 + j;
            if (row < M) {
                #pragma unroll
                for (int ni = 0; ni < 8; ++ni)
                    H1S[((size_t)ni * M + row) * 16 + lr] = f2bf(acc[mi][ni][j]);
            }
        }
}

// ---------------- GEMM2: h2s = bf16(g1rs @ W2), slice-major in/out ----------------
// A (g1rs) is slice-major [8][M][16] bf16 (relu pre-applied by spmm1).
// Output slice-major [8][M][8].

__global__ __launch_bounds__(256) void gemm2_mfma(const unsigned short* __restrict__ GS,
                                                  const unsigned short* __restrict__ W2T,
                                                  unsigned short* __restrict__ H2S, int M) {
    __shared__ __align__(16) unsigned short As[128 * 136];
    __shared__ __align__(16) unsigned short Bs[64 * 136];
    const int tid = threadIdx.x;
    const int lane = tid & 63;
    const int w = tid >> 6;
    const int row0 = blockIdx.x * 128;

    // stage A from slice-major: u in [0,2048) us8; slice=u>>8, v=u&255, row=v>>1, half=v&1
    #pragma unroll
    for (int l = 0; l < 8; ++l) {
        int u = tid + l * 256;
        int slice = u >> 8, v = u & 255, r = v >> 1, half = v & 1;
        int row = row0 + r;
        us8 val{};
        if (row < M) val = *reinterpret_cast<const us8*>(&GS[((size_t)slice * M + row) * 16 + half * 8]);
        *reinterpret_cast<us8*>(&As[r * 136 + slice * 16 + half * 8]) = val;
    }
    #pragma unroll
    for (int l = 0; l < 4; ++l) {
        int f = tid + l * 256;
        int n = f >> 4, k8 = f & 15;
        us8 v = *reinterpret_cast<const us8*>(&W2T[n * 128 + k8 * 8]);
        *reinterpret_cast<us8*>(&Bs[n * 136 + k8 * 8]) = v;
    }
    __syncthreads();

    f32x4 acc[2][4] = {};
    const int lr = lane & 15;
    const int kb = (lane >> 4) * 8;
    #pragma unroll
    for (int kk = 0; kk < 4; ++kk) {
        bfrag8 a0 = *reinterpret_cast<const bfrag8*>(&As[(w * 32 + lr) * 136 + kk * 32 + kb]);
        bfrag8 a1 = *reinterpret_cast<const bfrag8*>(&As[(w * 32 + 16 + lr) * 136 + kk * 32 + kb]);
        #pragma unroll
        for (int ni = 0; ni < 4; ++ni) {
            bfrag8 b = *reinterpret_cast<const bfrag8*>(&Bs[(ni * 16 + lr) * 136 + kk * 32 + kb]);
            acc[0][ni] = __builtin_amdgcn_mfma_f32_16x16x32_bf16(a0, b, acc[0][ni], 0, 0, 0);
            acc[1][ni] = __builtin_amdgcn_mfma_f32_16x16x32_bf16(a1, b, acc[1][ni], 0, 0, 0);
        }
    }
    // epilogue: feature ni*16+lr -> slice ni*2 + (lr>>3), f = lr&7
    const int rb = row0 + w * 32 + (lane >> 4) * 4;
    #pragma unroll
    for (int mi = 0; mi < 2; ++mi)
        #pragma unroll
        for (int j = 0; j < 4; ++j) {
            int row = rb + mi * 16 + j;
            if (row < M) {
                #pragma unroll
                for (int ni = 0; ni < 4; ++ni) {
                    int slice = ni * 2 + (lr >> 3);
                    H2S[((size_t)slice * M + row) * 8 + (lr & 7)] = f2bf(acc[mi][ni][j]);
                }
            }
        }
}

// ---------------- SpMM sliced, XCD-pinned ----------------
// Layer 1: slice = blockIdx%8 (16 feats, 3.2MB slice -> L2-resident on its XCD),
// 2 lanes/node, 128 nodes/block. Writes g1rs slice-major bf16(relu(acc)).

__global__ __launch_bounds__(256) void spmm_s1(const int* __restrict__ row_ptr,
                                               const int2* __restrict__ sval,
                                               const unsigned short* __restrict__ hs,
                                               unsigned short* __restrict__ outs, int n) {
    const int slice = blockIdx.x & 7;
    const int chunk = blockIdx.x >> 3;
    const int t = threadIdx.x;
    const int node = chunk * 128 + (t >> 1);
    if (node >= n) return;
    const int c8 = (t & 1) * 8;
    const unsigned short* hb = hs + (size_t)slice * n * 16 + c8;
    const int s = row_ptr[node], e = row_ptr[node + 1];
    float acc[8] = {};
    int i = s;
    for (; i + 4 <= e; i += 4) {
        int2 e0 = sval[i + 0], e1 = sval[i + 1], e2 = sval[i + 2], e3 = sval[i + 3];
        float v0 = __int_as_float(e0.y), v1 = __int_as_float(e1.y);
        float v2 = __int_as_float(e2.y), v3 = __int_as_float(e3.y);
        us8 m0 = *reinterpret_cast<const us8*>(&hb[(size_t)e0.x * 16]);
        us8 m1 = *reinterpret_cast<const us8*>(&hb[(size_t)e1.x * 16]);
        us8 m2 = *reinterpret_cast<const us8*>(&hb[(size_t)e2.x * 16]);
        us8 m3 = *reinterpret_cast<const us8*>(&hb[(size_t)e3.x * 16]);
        #pragma unroll
        for (int j = 0; j < 8; ++j) {
            acc[j] += v0 * bf2f(m0[j]);
            acc[j] += v1 * bf2f(m1[j]);
            acc[j] += v2 * bf2f(m2[j]);
            acc[j] += v3 * bf2f(m3[j]);
        }
    }
    for (; i < e; ++i) {
        int2 e0 = sval[i];
        float v = __int_as_float(e0.y);
        us8 m = *reinterpret_cast<const us8*>(&hb[(size_t)e0.x * 16]);
        #pragma unroll
        for (int j = 0; j < 8; ++j) acc[j] += v * bf2f(m[j]);
    }
    us8 o;
    #pragma unroll
    for (int j = 0; j < 8; ++j) o[j] = f2bf(fmaxf(acc[j], 0.f));
    *reinterpret_cast<us8*>(&outs[((size_t)slice * n + node) * 16 + c8]) = o;
}

// Layer 2: slice = blockIdx%8 (8 feats, 1.6MB slice), 1 lane/node, 256 nodes/block.
// Writes final f32 out[node*64 + slice*8 ..].

__global__ __launch_bounds__(256) void spmm_s2(const int* __restrict__ row_ptr,
                                               const int2* __restrict__ sval,
                                               const unsigned short* __restrict__ hs,
                                               float* __restrict__ out, int n) {
    const int slice = blockIdx.x & 7;
    const int chunk = blockIdx.x >> 3;
    const int node = chunk * 256 + threadIdx.x;
    if (node >= n) return;
    const unsigned short* hb = hs + (size_t)slice * n * 8;
    const int s = row_ptr[node], e = row_ptr[node + 1];
    float acc[8] = {};
    int i = s;
    for (; i + 4 <= e; i += 4) {
        int2 e0 = sval[i + 0], e1 = sval[i + 1], e2 = sval[i + 2], e3 = sval[i + 3];
        float v0 = __int_as_float(e0.y), v1 = __int_as_float(e1.y);
        float v2 = __int_as_float(e2.y), v3 = __int_as_float(e3.y);
        us8 m0 = *reinterpret_cast<const us8*>(&hb[(size_t)e0.x * 8]);
        us8 m1 = *reinterpret_cast<const us8*>(&hb[(size_t)e1.x * 8]);
        us8 m2 = *reinterpret_cast<const us8*>(&hb[(size_t)e2.x * 8]);
        us8 m3 = *reinterpret_cast<const us8*>(&hb[(size_t)e3.x * 8]);
        #pragma unroll
        for (int j = 0; j < 8; ++j) {
            acc[j] += v0 * bf2f(m0[j]);
            acc[j] += v1 * bf2f(m1[j]);
            acc[j] += v2 * bf2f(m2[j]);
            acc[j] += v3 * bf2f(m3[j]);
        }
    }
    for (; i < e; ++i) {
        int2 e0 = sval[i];
        float v = __int_as_float(e0.y);
        us8 m = *reinterpret_cast<const us8*>(&hb[(size_t)e0.x * 8]);
        #pragma unroll
        for (int j = 0; j < 8; ++j) acc[j] += v * bf2f(m[j]);
    }
    float* op = out + (size_t)node * 64 + slice * 8;
    *reinterpret_cast<float4*>(op) = make_float4(acc[0], acc[1], acc[2], acc[3]);
    *reinterpret_cast<float4*>(op + 4) = make_float4(acc[4], acc[5], acc[6], acc[7]);
}

// ---------------- launch ----------------

extern "C" void kernel_launch(void* const* d_in, const int* in_sizes, int n_in,
                              void* d_out, int out_size, void* d_ws, size_t ws_size,
                              hipStream_t stream) {
    const float* x  = (const float*)d_in[0];
    const float* W1 = (const float*)d_in[1];
    const float* W2 = (const float*)d_in[2];
    const float* ev = (const float*)d_in[3];
    const int*   ei = (const int*)d_in[4];

    const int N = in_sizes[0] / IN_CH;   // 100000
    const int E = in_sizes[3];           // 1600000
    const int* src = ei;
    const int* dst = ei + E;

    const int NBUCK = (N + 255) >> 8;                    // 391
    const int G1 = 256;                                  // level-1 blocks
    const int CH = (E + G1 - 1) / G1;                    // 6250 edges/block
    const int NB_TOT = NBUCK * G1;                       // 100096
    const int nchunk = (NB_TOT + 1023) / 1024;           // 98

    // workspace layout (~78 MB); h2s aliases h1s (dead after spmm_s1)
    unsigned short* h1s  = (unsigned short*)d_ws;        // [8][N][16] bf16
    unsigned short* g1rs = h1s + (size_t)N * HID_CH;     // [8][N][16] bf16 (relu)
    unsigned short* h2s  = h1s;                          // [8][N][8] bf16 (alias)
    unsigned short* w1t  = g1rs + (size_t)N * HID_CH;    // 128*128 bf16 [n][k]
    unsigned short* w2t  = w1t + 128 * 128;              // 64*128 bf16 [n][k]
    int2*  sval    = (int2*)(w2t + 64 * 128);            // E packed (src, val)
    int2*  ebuf    = sval + E;                           // E bucketed intermediate
    int*   row_ptr = (int*)(ebuf + E);                   // N+1
    int*   bcnt    = row_ptr + (N + 1);                  // NB_TOT (scan in place)
    int*   btot    = bcnt + NB_TOT;                      // 128
    int*   bb      = btot + 128;                         // NBUCK+1

    // CSR build (LDS atomics only)
    cnt1<<<G1, 256, 0, stream>>>(dst, bcnt, E, CH, NBUCK, G1);
    scanA<<<nchunk, 1024, 0, stream>>>(bcnt, bcnt, btot, NB_TOT);
    scanB<<<1, 128, 0, stream>>>(btot, nchunk);
    scanC2<<<nchunk, 1024, 0, stream>>>(bcnt, btot, NB_TOT);
    bbk<<<1, 512, 0, stream>>>(bcnt, bb, NBUCK, G1, E);
    scat1<<<G1, 256, 0, stream>>>(src, dst, ev, bcnt, ebuf, E, CH, NBUCK, G1);
    sort2<<<NBUCK, 256, 0, stream>>>(ebuf, bb, sval, row_ptr, N, NBUCK, E);

    // weights: cast + transpose to [n][k] bf16
    castT_w1<<<64, 256, 0, stream>>>(W1, w1t);
    castT_w2<<<32, 256, 0, stream>>>(W2, w2t);

    // layer 1
    gemm1_mfma<<<(N + 127) / 128, 256, 0, stream>>>(x, w1t, h1s, N);
    {
        const int nchunks = (N + 127) / 128;             // 782
        spmm_s1<<<nchunks * 8, 256, 0, stream>>>(row_ptr, sval, h1s, g1rs, N);
    }

    // layer 2
    gemm2_mfma<<<(N + 127) / 128, 256, 0, stream>>>(g1rs, w2t, h2s, N);
    {
        const int nchunks = (N + 255) / 256;             // 391
        spmm_s2<<<nchunks * 8, 256, 0, stream>>>(row_ptr, sval, h2s, (float*)d_out, N);
    }
}